// Round 1
// baseline (10926.945 us; speedup 1.0000x reference)
//
#include <hip/hip_runtime.h>

#define USER_NUM 100000
#define ITEM_NUM 50000
#define D 64
#define DV 16   // float4 per row

// d_out init: out[0:2.4M f4) = concat(user_emb, item_emb); zero the next-buffers.
__global__ void init_kernel(const float4* __restrict__ ue, const float4* __restrict__ ie,
                            float4* __restrict__ out, float4* __restrict__ zbase) {
    int idx = blockIdx.x * 256 + threadIdx.x;
    const int NU4 = USER_NUM * DV;            // 1.6M
    const int NT4 = NU4 + ITEM_NUM * DV;      // 2.4M
    if (idx < NT4) {
        out[idx] = (idx < NU4) ? ue[idx] : ie[idx - NU4];
        zbase[idx] = make_float4(0.f, 0.f, 0.f, 0.f);
    }
}

// One-directional COO spmm scatter: out[rows[e]] += vals[e] * x[cols[e]]
__global__ void scatter1_kernel(const int* __restrict__ rows, const int* __restrict__ cols,
                                const float* __restrict__ vals,
                                const float4* __restrict__ x, float* __restrict__ out,
                                int nnz) {
    int gid = blockIdx.x * 256 + threadIdx.x;
    int e = gid >> 4;
    if (e >= nnz) return;
    int lane = gid & 15;
    int r = rows[e];
    int c = cols[e];
    float v = vals[e];
    float4 xv = x[c * DV + lane];
    float* dst = out + r * D + lane * 4;
    atomicAdd(dst + 0, v * xv.x);
    atomicAdd(dst + 1, v * xv.y);
    atomicAdd(dst + 2, v * xv.z);
    atomicAdd(dst + 3, v * xv.w);
}

// Fused bidirectional ui scatter:
//   u_next[r] += v * i_cur[c];  i_next[c] += v * u_cur[r]
__global__ void scatter_ui_kernel(const int* __restrict__ rows, const int* __restrict__ cols,
                                  const float* __restrict__ vals,
                                  const float4* __restrict__ u_cur, const float4* __restrict__ i_cur,
                                  float* __restrict__ u_next, float* __restrict__ i_next,
                                  int nnz) {
    int gid = blockIdx.x * 256 + threadIdx.x;
    int e = gid >> 4;
    if (e >= nnz) return;
    int lane = gid & 15;
    int r = rows[e];
    int c = cols[e];
    float v = vals[e];
    float4 uv = u_cur[r * DV + lane];
    float4 iv = i_cur[c * DV + lane];
    float* du = u_next + r * D + lane * 4;
    float* di = i_next + c * D + lane * 4;
    atomicAdd(du + 0, v * iv.x);
    atomicAdd(du + 1, v * iv.y);
    atomicAdd(du + 2, v * iv.z);
    atomicAdd(du + 3, v * iv.w);
    atomicAdd(di + 0, v * uv.x);
    atomicAdd(di + 1, v * uv.y);
    atomicAdd(di + 2, v * uv.z);
    atomicAdd(di + 3, v * uv.w);
}

// combine: h = 0.5*next; cur = h (if store_cur); outsum = (outsum + h)*final_scale;
// also zeroes next in place so the following layer needs no memset.
__global__ void combine_kernel(float4* __restrict__ next, float4* __restrict__ cur,
                               float4* __restrict__ outsum, int n4,
                               float final_scale, int store_cur) {
    int i = blockIdx.x * 256 + threadIdx.x;
    if (i >= n4) return;
    float4 nx = next[i];
    next[i] = make_float4(0.f, 0.f, 0.f, 0.f);
    float4 h;
    h.x = 0.5f * nx.x; h.y = 0.5f * nx.y; h.z = 0.5f * nx.z; h.w = 0.5f * nx.w;
    if (store_cur) cur[i] = h;
    float4 o = outsum[i];
    o.x = (o.x + h.x) * final_scale;
    o.y = (o.y + h.y) * final_scale;
    o.z = (o.z + h.z) * final_scale;
    o.w = (o.w + h.w) * final_scale;
    outsum[i] = o;
}

extern "C" void kernel_launch(void* const* d_in, const int* in_sizes, int n_in,
                              void* d_out, int out_size, void* d_ws, size_t ws_size,
                              hipStream_t stream) {
    const float* ue      = (const float*)d_in[0];
    const float* ie      = (const float*)d_in[1];
    const float* uu_val  = (const float*)d_in[2];
    const float* ui_val  = (const float*)d_in[3];
    const float* ii_val  = (const float*)d_in[4];
    const int*   uu_rows = (const int*)d_in[5];
    const int*   uu_cols = (const int*)d_in[6];
    const int*   ui_rows = (const int*)d_in[7];
    const int*   ui_cols = (const int*)d_in[8];
    const int*   ii_rows = (const int*)d_in[9];
    const int*   ii_cols = (const int*)d_in[10];

    const int NNZ_UU = in_sizes[2];
    const int NNZ_UI = in_sizes[3];
    const int NNZ_II = in_sizes[4];

    float* out_u = (float*)d_out;                       // USER_NUM*64
    float* out_i = out_u + USER_NUM * D;                // ITEM_NUM*64

    float* ws     = (float*)d_ws;
    float* u_cur  = ws;                                 // USER_NUM*64
    float* i_cur  = u_cur + USER_NUM * D;               // ITEM_NUM*64
    float* u_next = i_cur + ITEM_NUM * D;               // USER_NUM*64
    float* i_next = u_next + USER_NUM * D;              // ITEM_NUM*64

    const int NU4 = USER_NUM * DV;                      // 1.6M float4
    const int NI4 = ITEM_NUM * DV;                      // 0.8M float4
    const int NT4 = NU4 + NI4;                          // 2.4M float4

    // init: d_out = concat(embeddings); zero u_next/i_next (contiguous)
    init_kernel<<<(NT4 + 255) / 256, 256, 0, stream>>>(
        (const float4*)ue, (const float4*)ie, (float4*)d_out, (float4*)u_next);

    const float inv3 = 1.0f / 3.0f;

    // ---- layer 1: cur = raw embeddings ----
    scatter_ui_kernel<<<(NNZ_UI * 16 + 255) / 256, 256, 0, stream>>>(
        ui_rows, ui_cols, ui_val, (const float4*)ue, (const float4*)ie,
        u_next, i_next, NNZ_UI);
    scatter1_kernel<<<(NNZ_UU * 16 + 255) / 256, 256, 0, stream>>>(
        uu_rows, uu_cols, uu_val, (const float4*)ue, u_next, NNZ_UU);
    scatter1_kernel<<<(NNZ_II * 16 + 255) / 256, 256, 0, stream>>>(
        ii_rows, ii_cols, ii_val, (const float4*)ie, i_next, NNZ_II);
    combine_kernel<<<(NU4 + 255) / 256, 256, 0, stream>>>(
        (float4*)u_next, (float4*)u_cur, (float4*)out_u, NU4, 1.0f, 1);
    combine_kernel<<<(NI4 + 255) / 256, 256, 0, stream>>>(
        (float4*)i_next, (float4*)i_cur, (float4*)out_i, NI4, 1.0f, 1);

    // ---- layer 2: cur = u_cur/i_cur; final combine folds the 1/3 mean ----
    scatter_ui_kernel<<<(NNZ_UI * 16 + 255) / 256, 256, 0, stream>>>(
        ui_rows, ui_cols, ui_val, (const float4*)u_cur, (const float4*)i_cur,
        u_next, i_next, NNZ_UI);
    scatter1_kernel<<<(NNZ_UU * 16 + 255) / 256, 256, 0, stream>>>(
        uu_rows, uu_cols, uu_val, (const float4*)u_cur, u_next, NNZ_UU);
    scatter1_kernel<<<(NNZ_II * 16 + 255) / 256, 256, 0, stream>>>(
        ii_rows, ii_cols, ii_val, (const float4*)i_cur, i_next, NNZ_II);
    combine_kernel<<<(NU4 + 255) / 256, 256, 0, stream>>>(
        (float4*)u_next, (float4*)u_cur, (float4*)out_u, NU4, inv3, 0);
    combine_kernel<<<(NI4 + 255) / 256, 256, 0, stream>>>(
        (float4*)i_next, (float4*)i_cur, (float4*)out_i, NI4, inv3, 0);
}

// Round 2
// 2128.808 us; speedup vs baseline: 5.1329x; 5.1329x over previous
//
#include <hip/hip_runtime.h>

#define NU 100000
#define NI 50000
#define D 64
#define NU4 (NU * 16)   // float4 count, user table
#define NI4 (NI * 16)
#define NT4 (NU4 + NI4)

// out = concat(ue, ie); u_cur = ue; i_cur = ie
__global__ void init_kernel(const float4* __restrict__ ue, const float4* __restrict__ ie,
                            float4* __restrict__ out,
                            float4* __restrict__ ucur, float4* __restrict__ icur) {
    int idx = blockIdx.x * 256 + threadIdx.x;
    if (idx < NU4) {
        float4 v = ue[idx];
        out[idx] = v;
        ucur[idx] = v;
    } else if (idx < NT4) {
        float4 v = ie[idx - NU4];
        out[idx] = v;
        icur[idx - NU4] = v;
    }
}

__global__ void hist_kernel(const int* __restrict__ dest, int* __restrict__ counts, int nnz) {
    int e = blockIdx.x * 256 + threadIdx.x;
    if (e < nnz) atomicAdd(&counts[dest[e]], 1);
}

// single-block exclusive scan: counts[0..n) -> ptr[0..n], fill[0..n) = ptr[0..n)
__global__ void scan_kernel(const int* __restrict__ counts, int* __restrict__ ptr,
                            int* __restrict__ fill, int n) {
    __shared__ int smem[1024];
    __shared__ int carry;
    if (threadIdx.x == 0) carry = 0;
    __syncthreads();
    for (int base = 0; base < n; base += 1024) {
        int i = base + (int)threadIdx.x;
        int x = (i < n) ? counts[i] : 0;
        smem[threadIdx.x] = x;
        __syncthreads();
        for (int off = 1; off < 1024; off <<= 1) {
            int t = (threadIdx.x >= (unsigned)off) ? smem[threadIdx.x - off] : 0;
            __syncthreads();
            smem[threadIdx.x] += t;
            __syncthreads();
        }
        int incl = smem[threadIdx.x];
        int excl = incl - x + carry;
        if (i < n) { ptr[i] = excl; fill[i] = excl; }
        __syncthreads();
        if (threadIdx.x == 1023) carry += incl;
        __syncthreads();
    }
    if (threadIdx.x == 0) ptr[n] = carry;
}

// packed[slot] = (src, val) bucketed by dest
__global__ void build_kernel(const int* __restrict__ dest, const int* __restrict__ src,
                             const float* __restrict__ val,
                             int* __restrict__ fill, int2* __restrict__ packed, int nnz) {
    int e = blockIdx.x * 256 + threadIdx.x;
    if (e >= nnz) return;
    int slot = atomicAdd(&fill[dest[e]], 1);
    packed[slot] = make_int2(src[e], __float_as_int(val[e]));
}

// One wave per output row, lane = feature.
// h = 0.5 * (A@srcA + B@srcB)[row]; next[row]=h (if store_next); out[row]=(out[row]+h)*final_scale
__global__ void spmm_fused(const int* __restrict__ ptrA, const int2* __restrict__ pkA,
                           const float* __restrict__ srcA,
                           const int* __restrict__ ptrB, const int2* __restrict__ pkB,
                           const float* __restrict__ srcB,
                           float* __restrict__ next, float* __restrict__ outsum,
                           int nrows, float final_scale, int store_next) {
    int wave = (int)((blockIdx.x * blockDim.x + threadIdx.x) >> 6);
    int lane = threadIdx.x & 63;
    if (wave >= nrows) return;
    float acc = 0.f;

    int b = ptrA[wave], e = ptrA[wave + 1];
    int j = b;
    for (; j + 1 < e; j += 2) {
        int2 p0 = pkA[j];
        int2 p1 = pkA[j + 1];
        float x0 = srcA[p0.x * D + lane];
        float x1 = srcA[p1.x * D + lane];
        acc += __int_as_float(p0.y) * x0;
        acc += __int_as_float(p1.y) * x1;
    }
    if (j < e) {
        int2 p = pkA[j];
        acc += __int_as_float(p.y) * srcA[p.x * D + lane];
    }

    b = ptrB[wave]; e = ptrB[wave + 1];
    j = b;
    for (; j + 1 < e; j += 2) {
        int2 p0 = pkB[j];
        int2 p1 = pkB[j + 1];
        float x0 = srcB[p0.x * D + lane];
        float x1 = srcB[p1.x * D + lane];
        acc += __int_as_float(p0.y) * x0;
        acc += __int_as_float(p1.y) * x1;
    }
    if (j < e) {
        int2 p = pkB[j];
        acc += __int_as_float(p.y) * srcB[p.x * D + lane];
    }

    float h = 0.5f * acc;
    int o = wave * D + lane;
    if (store_next) next[o] = h;
    outsum[o] = (outsum[o] + h) * final_scale;
}

extern "C" void kernel_launch(void* const* d_in, const int* in_sizes, int n_in,
                              void* d_out, int out_size, void* d_ws, size_t ws_size,
                              hipStream_t stream) {
    const float* ue      = (const float*)d_in[0];
    const float* ie      = (const float*)d_in[1];
    const float* uu_val  = (const float*)d_in[2];
    const float* ui_val  = (const float*)d_in[3];
    const float* ii_val  = (const float*)d_in[4];
    const int*   uu_rows = (const int*)d_in[5];
    const int*   uu_cols = (const int*)d_in[6];
    const int*   ui_rows = (const int*)d_in[7];
    const int*   ui_cols = (const int*)d_in[8];
    const int*   ii_rows = (const int*)d_in[9];
    const int*   ii_cols = (const int*)d_in[10];

    const int NNZ_UU = in_sizes[2];
    const int NNZ_UI = in_sizes[3];
    const int NNZ_II = in_sizes[4];

    float* out_u = (float*)d_out;
    float* out_i = out_u + (size_t)NU * D;

    // ---- workspace layout (4-byte words) ----
    float* wsf = (float*)d_ws;
    float* u_cur  = wsf;                       // NU*D
    float* i_cur  = u_cur + (size_t)NU * D;    // NI*D
    float* u_next = i_cur + (size_t)NI * D;    // NU*D
    float* i_next = u_next + (size_t)NU * D;   // NI*D
    int2*  pk_uiR = (int2*)(i_next + (size_t)NI * D);   // NNZ_UI
    int2*  pk_uiC = pk_uiR + NNZ_UI;                    // NNZ_UI
    int2*  pk_uu  = pk_uiC + NNZ_UI;                    // NNZ_UU
    int2*  pk_ii  = pk_uu + NNZ_UU;                     // NNZ_II
    int*   ptr_uiR = (int*)(pk_ii + NNZ_II);   // NU+1
    int*   ptr_uiC = ptr_uiR + (NU + 1);       // NI+1
    int*   ptr_uu  = ptr_uiC + (NI + 1);       // NU+1
    int*   ptr_ii  = ptr_uu + (NU + 1);        // NI+1
    int*   fill_uiR = ptr_ii + (NI + 1);       // NU
    int*   fill_uiC = fill_uiR + NU;           // NI
    int*   fill_uu  = fill_uiC + NI;           // NU
    int*   fill_ii  = fill_uu + NU;            // NI
    int*   cnt_uiR  = fill_ii + NI;            // NU   (counts block, contiguous)
    int*   cnt_uiC  = cnt_uiR + NU;            // NI
    int*   cnt_uu   = cnt_uiC + NI;            // NU
    int*   cnt_ii   = cnt_uu + NU;             // NI

    // zero the counts block (2*(NU+NI) ints, contiguous)
    hipMemsetAsync(cnt_uiR, 0, sizeof(int) * (size_t)(2 * (NU + NI)), stream);

    // init dense state + output
    init_kernel<<<(NT4 + 255) / 256, 256, 0, stream>>>(
        (const float4*)ue, (const float4*)ie, (float4*)d_out,
        (float4*)u_cur, (float4*)i_cur);

    // ---- CSR build (index-only work, once per launch) ----
    hist_kernel<<<(NNZ_UI + 255) / 256, 256, 0, stream>>>(ui_rows, cnt_uiR, NNZ_UI);
    hist_kernel<<<(NNZ_UI + 255) / 256, 256, 0, stream>>>(ui_cols, cnt_uiC, NNZ_UI);
    hist_kernel<<<(NNZ_UU + 255) / 256, 256, 0, stream>>>(uu_rows, cnt_uu, NNZ_UU);
    hist_kernel<<<(NNZ_II + 255) / 256, 256, 0, stream>>>(ii_rows, cnt_ii, NNZ_II);

    scan_kernel<<<1, 1024, 0, stream>>>(cnt_uiR, ptr_uiR, fill_uiR, NU);
    scan_kernel<<<1, 1024, 0, stream>>>(cnt_uiC, ptr_uiC, fill_uiC, NI);
    scan_kernel<<<1, 1024, 0, stream>>>(cnt_uu,  ptr_uu,  fill_uu,  NU);
    scan_kernel<<<1, 1024, 0, stream>>>(cnt_ii,  ptr_ii,  fill_ii,  NI);

    build_kernel<<<(NNZ_UI + 255) / 256, 256, 0, stream>>>(ui_rows, ui_cols, ui_val, fill_uiR, pk_uiR, NNZ_UI);
    build_kernel<<<(NNZ_UI + 255) / 256, 256, 0, stream>>>(ui_cols, ui_rows, ui_val, fill_uiC, pk_uiC, NNZ_UI);
    build_kernel<<<(NNZ_UU + 255) / 256, 256, 0, stream>>>(uu_rows, uu_cols, uu_val, fill_uu, pk_uu, NNZ_UU);
    build_kernel<<<(NNZ_II + 255) / 256, 256, 0, stream>>>(ii_rows, ii_cols, ii_val, fill_ii, pk_ii, NNZ_II);

    // ---- layer 1: read u_cur/i_cur, write u_next/i_next, out += h ----
    {
        int ublocks = (NU * 64 + 255) / 256;   // 4 rows (waves) per block
        int iblocks = (NI * 64 + 255) / 256;
        spmm_fused<<<ublocks, 256, 0, stream>>>(
            ptr_uu, pk_uu, u_cur, ptr_uiR, pk_uiR, i_cur,
            u_next, out_u, NU, 1.0f, 1);
        spmm_fused<<<iblocks, 256, 0, stream>>>(
            ptr_ii, pk_ii, i_cur, ptr_uiC, pk_uiC, u_cur,
            i_next, out_i, NI, 1.0f, 1);
    }

    // ---- layer 2: read u_next/i_next, out = (out + h) / 3 ----
    {
        int ublocks = (NU * 64 + 255) / 256;
        int iblocks = (NI * 64 + 255) / 256;
        const float inv3 = 1.0f / 3.0f;
        spmm_fused<<<ublocks, 256, 0, stream>>>(
            ptr_uu, pk_uu, u_next, ptr_uiR, pk_uiR, i_next,
            u_cur, out_u, NU, inv3, 0);
        spmm_fused<<<iblocks, 256, 0, stream>>>(
            ptr_ii, pk_ii, i_next, ptr_uiC, pk_uiC, u_next,
            i_cur, out_i, NI, inv3, 0);
    }
}

// Round 3
// 1104.969 us; speedup vs baseline: 9.8889x; 1.9266x over previous
//
#include <hip/hip_runtime.h>

#define NU 100000
#define NI 50000
#define D 64
#define NTOT (2 * (NU + NI))          // concatenated count array: uiR | uiC | uu | ii
#define B_UIR 0
#define B_UIC (NU)
#define B_UU  (NU + NI)
#define B_II  (2 * NU + NI)
#define NB    ((NTOT + 1023) / 1024)  // scan blocks (1024 elems each) = 293
#define NU4 (NU * 16)
#define NI4 (NI * 16)
#define NT4 (NU4 + NI4)

// out = concat(ue, ie); u_cur = ue; i_cur = ie
__global__ void init_kernel(const float4* __restrict__ ue, const float4* __restrict__ ie,
                            float4* __restrict__ out,
                            float4* __restrict__ ucur, float4* __restrict__ icur) {
    int idx = blockIdx.x * 256 + threadIdx.x;
    if (idx < NU4) {
        float4 v = ue[idx];
        out[idx] = v;
        ucur[idx] = v;
    } else if (idx < NT4) {
        float4 v = ie[idx - NU4];
        out[idx] = v;
        icur[idx - NU4] = v;
    }
}

// ui histogram both directions; rank = old count (intra-bucket slot)
__global__ void hist_ui_kernel(const int* __restrict__ rows, const int* __restrict__ cols,
                               int* __restrict__ cnt,
                               int* __restrict__ rankR, int* __restrict__ rankC, int nnz) {
    int e = blockIdx.x * 256 + threadIdx.x;
    if (e >= nnz) return;
    rankR[e] = atomicAdd(&cnt[B_UIR + rows[e]], 1);
    rankC[e] = atomicAdd(&cnt[B_UIC + cols[e]], 1);
}

__global__ void hist1_kernel(const int* __restrict__ dest, int* __restrict__ cnt_base,
                             int* __restrict__ rank, int nnz) {
    int e = blockIdx.x * 256 + threadIdx.x;
    if (e >= nnz) return;
    rank[e] = atomicAdd(&cnt_base[dest[e]], 1);
}

// ---- hierarchical exclusive scan over cnt[0..NTOT) ----
__global__ void scan_reduce(const int* __restrict__ cnt, int* __restrict__ bsum) {
    __shared__ int s[256];
    int tid = threadIdx.x;
    int base = blockIdx.x * 1024 + tid * 4;
    int sum = 0;
#pragma unroll
    for (int k = 0; k < 4; k++) {
        int i = base + k;
        if (i < NTOT) sum += cnt[i];
    }
    s[tid] = sum;
    __syncthreads();
    for (int off = 128; off > 0; off >>= 1) {
        if (tid < off) s[tid] += s[tid + off];
        __syncthreads();
    }
    if (tid == 0) bsum[blockIdx.x] = s[0];
}

__global__ void scan_top(const int* __restrict__ bsum, int* __restrict__ bscan,
                         int* __restrict__ ptr) {
    __shared__ int s[512];
    int tid = threadIdx.x;
    int x = (tid < NB) ? bsum[tid] : 0;
    s[tid] = x;
    __syncthreads();
    for (int off = 1; off < 512; off <<= 1) {
        int t = (tid >= off) ? s[tid - off] : 0;
        __syncthreads();
        s[tid] += t;
        __syncthreads();
    }
    if (tid < NB) bscan[tid] = s[tid] - x;   // exclusive
    if (tid == 511) ptr[NTOT] = s[511];      // total nnz
}

__global__ void scan_write(const int* __restrict__ cnt, const int* __restrict__ bscan,
                           int* __restrict__ ptr) {
    __shared__ int s[256];
    int tid = threadIdx.x;
    int base = blockIdx.x * 1024 + tid * 4;
    int c[4];
    int sum = 0;
#pragma unroll
    for (int k = 0; k < 4; k++) {
        int i = base + k;
        c[k] = (i < NTOT) ? cnt[i] : 0;
        sum += c[k];
    }
    s[tid] = sum;
    __syncthreads();
    for (int off = 1; off < 256; off <<= 1) {
        int t = (tid >= off) ? s[tid - off] : 0;
        __syncthreads();
        s[tid] += t;
        __syncthreads();
    }
    int run = s[tid] - sum + bscan[blockIdx.x];
#pragma unroll
    for (int k = 0; k < 4; k++) {
        int i = base + k;
        if (i < NTOT) ptr[i] = run;
        run += c[k];
    }
}

// ---- atomic-free bucket fill using precomputed ranks ----
__global__ void build_ui_kernel(const int* __restrict__ rows, const int* __restrict__ cols,
                                const float* __restrict__ val,
                                const int* __restrict__ rankR, const int* __restrict__ rankC,
                                const int* __restrict__ ptr, int2* __restrict__ pk, int nnz) {
    int e = blockIdx.x * 256 + threadIdx.x;
    if (e >= nnz) return;
    int r = rows[e], c = cols[e];
    int vb = __float_as_int(val[e]);
    pk[ptr[B_UIR + r] + rankR[e]] = make_int2(c, vb);
    pk[ptr[B_UIC + c] + rankC[e]] = make_int2(r, vb);
}

__global__ void build1_kernel(const int* __restrict__ dest, const int* __restrict__ src,
                              const float* __restrict__ val, const int* __restrict__ rank,
                              const int* __restrict__ ptr_base, int2* __restrict__ pk, int nnz) {
    int e = blockIdx.x * 256 + threadIdx.x;
    if (e >= nnz) return;
    pk[ptr_base[dest[e]] + rank[e]] = make_int2(src[e], __float_as_int(val[e]));
}

// 4-deep masked gather segment: acc += sum val*src[row]
__device__ __forceinline__ void acc_seg(int b, int e, const int2* __restrict__ pk,
                                        const float* __restrict__ src, int lane, float& acc) {
    for (int j = b; j < e; j += 4) {
        int j1 = (j + 1 < e) ? j + 1 : j;
        int j2 = (j + 2 < e) ? j + 2 : j;
        int j3 = (j + 3 < e) ? j + 3 : j;
        int2 q0 = pk[j];
        int2 q1 = pk[j1];
        int2 q2 = pk[j2];
        int2 q3 = pk[j3];
        float v0 = __int_as_float(q0.y);
        float v1 = (j + 1 < e) ? __int_as_float(q1.y) : 0.f;
        float v2 = (j + 2 < e) ? __int_as_float(q2.y) : 0.f;
        float v3 = (j + 3 < e) ? __int_as_float(q3.y) : 0.f;
        float x0 = src[q0.x * D + lane];
        float x1 = src[q1.x * D + lane];
        float x2 = src[q2.x * D + lane];
        float x3 = src[q3.x * D + lane];
        acc += v0 * x0;
        acc += v1 * x1;
        acc += v2 * x2;
        acc += v3 * x3;
    }
}

// One wave per output row (user rows then item rows), lane = feature.
__global__ void spmm_fused(const int* __restrict__ ptr, const int2* __restrict__ pk,
                           const float* __restrict__ usrc, const float* __restrict__ isrc,
                           float* __restrict__ unext, float* __restrict__ inext,
                           float* __restrict__ outsum, float final_scale, int store_next) {
    int wave = (int)((blockIdx.x * 256 + threadIdx.x) >> 6);
    int lane = threadIdx.x & 63;
    if (wave >= NU + NI) return;

    const float* srcA;
    const float* srcB;
    int iA, iB;
    float* dst;
    float* op;
    if (wave < NU) {
        iA = B_UU + wave;                       // uu graph
        iB = B_UIR + wave;                      // ui by-row
        srcA = usrc; srcB = isrc;
        dst = unext + (size_t)wave * D;
        op  = outsum + (size_t)wave * D;
    } else {
        int r = wave - NU;
        iA = B_II + r;                          // ii graph
        iB = B_UIC + r;                         // ui by-col
        srcA = isrc; srcB = usrc;
        dst = inext + (size_t)r * D;
        op  = outsum + (size_t)NU * D + (size_t)r * D;
    }

    float acc = 0.f;
    acc_seg(ptr[iA], ptr[iA + 1], pk, srcA, lane, acc);
    acc_seg(ptr[iB], ptr[iB + 1], pk, srcB, lane, acc);

    float h = 0.5f * acc;
    if (store_next) dst[lane] = h;
    op[lane] = (op[lane] + h) * final_scale;
}

extern "C" void kernel_launch(void* const* d_in, const int* in_sizes, int n_in,
                              void* d_out, int out_size, void* d_ws, size_t ws_size,
                              hipStream_t stream) {
    const float* ue      = (const float*)d_in[0];
    const float* ie      = (const float*)d_in[1];
    const float* uu_val  = (const float*)d_in[2];
    const float* ui_val  = (const float*)d_in[3];
    const float* ii_val  = (const float*)d_in[4];
    const int*   uu_rows = (const int*)d_in[5];
    const int*   uu_cols = (const int*)d_in[6];
    const int*   ui_rows = (const int*)d_in[7];
    const int*   ui_cols = (const int*)d_in[8];
    const int*   ii_rows = (const int*)d_in[9];
    const int*   ii_cols = (const int*)d_in[10];

    const int NNZ_UU = in_sizes[2];
    const int NNZ_UI = in_sizes[3];
    const int NNZ_II = in_sizes[4];
    const int NNZT   = 2 * NNZ_UI + NNZ_UU + NNZ_II;

    float* out = (float*)d_out;

    // ---- workspace layout ----
    float* wsf = (float*)d_ws;
    float* u_cur  = wsf;                        // NU*D
    float* i_cur  = u_cur + (size_t)NU * D;     // NI*D
    float* u_next = i_cur + (size_t)NI * D;     // NU*D
    float* i_next = u_next + (size_t)NU * D;    // NI*D
    int2*  pk     = (int2*)(i_next + (size_t)NI * D);   // NNZT int2 (8B-aligned: 19.2M floats)
    int*   ptr    = (int*)(pk + NNZT);          // NTOT+1
    int*   cnt    = ptr + (NTOT + 1);           // NTOT
    int*   bsum   = cnt + NTOT;                 // NB
    int*   bscan  = bsum + NB;                  // NB
    // rank arrays alias u_next (only live between hist and build; u_next written later)
    int* rankR  = (int*)u_next;                 // NNZ_UI
    int* rankC  = rankR + NNZ_UI;               // NNZ_UI
    int* rankUU = rankC + NNZ_UI;               // NNZ_UU
    int* rankII = rankUU + NNZ_UU;              // NNZ_II  (total 6.4M ints <= u_next's 6.4M floats... fits exactly)

    hipMemsetAsync(cnt, 0, sizeof(int) * (size_t)NTOT, stream);

    init_kernel<<<(NT4 + 255) / 256, 256, 0, stream>>>(
        (const float4*)ue, (const float4*)ie, (float4*)out,
        (float4*)u_cur, (float4*)i_cur);

    // histograms (+ intra-bucket ranks)
    hist_ui_kernel<<<(NNZ_UI + 255) / 256, 256, 0, stream>>>(
        ui_rows, ui_cols, cnt, rankR, rankC, NNZ_UI);
    hist1_kernel<<<(NNZ_UU + 255) / 256, 256, 0, stream>>>(
        uu_rows, cnt + B_UU, rankUU, NNZ_UU);
    hist1_kernel<<<(NNZ_II + 255) / 256, 256, 0, stream>>>(
        ii_rows, cnt + B_II, rankII, NNZ_II);

    // hierarchical exclusive scan of all 4 count blocks at once
    scan_reduce<<<NB, 256, 0, stream>>>(cnt, bsum);
    scan_top<<<1, 512, 0, stream>>>(bsum, bscan, ptr);
    scan_write<<<NB, 256, 0, stream>>>(cnt, bscan, ptr);

    // atomic-free packed-edge fill
    build_ui_kernel<<<(NNZ_UI + 255) / 256, 256, 0, stream>>>(
        ui_rows, ui_cols, ui_val, rankR, rankC, ptr, pk, NNZ_UI);
    build1_kernel<<<(NNZ_UU + 255) / 256, 256, 0, stream>>>(
        uu_rows, uu_cols, uu_val, rankUU, ptr + B_UU, pk, NNZ_UU);
    build1_kernel<<<(NNZ_II + 255) / 256, 256, 0, stream>>>(
        ii_rows, ii_cols, ii_val, rankII, ptr + B_II, pk, NNZ_II);

    // ---- layer 1: cur -> next, out += h ----
    int blocks = ((NU + NI) * 64 + 255) / 256;
    spmm_fused<<<blocks, 256, 0, stream>>>(
        ptr, pk, u_cur, i_cur, u_next, i_next, out, 1.0f, 1);

    // ---- layer 2: next -> (discard), out = (out + h)/3 ----
    spmm_fused<<<blocks, 256, 0, stream>>>(
        ptr, pk, u_next, i_next, u_cur, i_cur, out, 1.0f / 3.0f, 0);
}

// Round 4
// 996.865 us; speedup vs baseline: 10.9613x; 1.1084x over previous
//
#include <hip/hip_runtime.h>

#define NU 100000
#define NI 50000
#define D 64
#define DV4 16                         // float4 per row
#define NTOT (2 * (NU + NI))          // concatenated count array: uiR | uiC | uu | ii
#define B_UIR 0
#define B_UIC (NU)
#define B_UU  (NU + NI)
#define B_II  (2 * NU + NI)
#define NB    ((NTOT + 1023) / 1024)  // scan blocks (1024 elems each) = 293
#define NU4 (NU * 16)
#define NI4 (NI * 16)
#define NT4 (NU4 + NI4)

// out = concat(ue, ie); u_cur = ue; i_cur = ie
__global__ void init_kernel(const float4* __restrict__ ue, const float4* __restrict__ ie,
                            float4* __restrict__ out,
                            float4* __restrict__ ucur, float4* __restrict__ icur) {
    int idx = blockIdx.x * 256 + threadIdx.x;
    if (idx < NU4) {
        float4 v = ue[idx];
        out[idx] = v;
        ucur[idx] = v;
    } else if (idx < NT4) {
        float4 v = ie[idx - NU4];
        out[idx] = v;
        icur[idx - NU4] = v;
    }
}

// ui histogram both directions; rank = old count (intra-bucket slot)
__global__ void hist_ui_kernel(const int* __restrict__ rows, const int* __restrict__ cols,
                               int* __restrict__ cnt,
                               int* __restrict__ rankR, int* __restrict__ rankC, int nnz) {
    int e = blockIdx.x * 256 + threadIdx.x;
    if (e >= nnz) return;
    rankR[e] = atomicAdd(&cnt[B_UIR + rows[e]], 1);
    rankC[e] = atomicAdd(&cnt[B_UIC + cols[e]], 1);
}

__global__ void hist1_kernel(const int* __restrict__ dest, int* __restrict__ cnt_base,
                             int* __restrict__ rank, int nnz) {
    int e = blockIdx.x * 256 + threadIdx.x;
    if (e >= nnz) return;
    rank[e] = atomicAdd(&cnt_base[dest[e]], 1);
}

// ---- hierarchical exclusive scan over cnt[0..NTOT) ----
__global__ void scan_reduce(const int* __restrict__ cnt, int* __restrict__ bsum) {
    __shared__ int s[256];
    int tid = threadIdx.x;
    int base = blockIdx.x * 1024 + tid * 4;
    int sum = 0;
#pragma unroll
    for (int k = 0; k < 4; k++) {
        int i = base + k;
        if (i < NTOT) sum += cnt[i];
    }
    s[tid] = sum;
    __syncthreads();
    for (int off = 128; off > 0; off >>= 1) {
        if (tid < off) s[tid] += s[tid + off];
        __syncthreads();
    }
    if (tid == 0) bsum[blockIdx.x] = s[0];
}

__global__ void scan_top(const int* __restrict__ bsum, int* __restrict__ bscan,
                         int* __restrict__ ptr) {
    __shared__ int s[512];
    int tid = threadIdx.x;
    int x = (tid < NB) ? bsum[tid] : 0;
    s[tid] = x;
    __syncthreads();
    for (int off = 1; off < 512; off <<= 1) {
        int t = (tid >= off) ? s[tid - off] : 0;
        __syncthreads();
        s[tid] += t;
        __syncthreads();
    }
    if (tid < NB) bscan[tid] = s[tid] - x;   // exclusive
    if (tid == 511) ptr[NTOT] = s[511];      // total nnz
}

__global__ void scan_write(const int* __restrict__ cnt, const int* __restrict__ bscan,
                           int* __restrict__ ptr) {
    __shared__ int s[256];
    int tid = threadIdx.x;
    int base = blockIdx.x * 1024 + tid * 4;
    int c[4];
    int sum = 0;
#pragma unroll
    for (int k = 0; k < 4; k++) {
        int i = base + k;
        c[k] = (i < NTOT) ? cnt[i] : 0;
        sum += c[k];
    }
    s[tid] = sum;
    __syncthreads();
    for (int off = 1; off < 256; off <<= 1) {
        int t = (tid >= off) ? s[tid - off] : 0;
        __syncthreads();
        s[tid] += t;
        __syncthreads();
    }
    int run = s[tid] - sum + bscan[blockIdx.x];
#pragma unroll
    for (int k = 0; k < 4; k++) {
        int i = base + k;
        if (i < NTOT) ptr[i] = run;
        run += c[k];
    }
}

// ---- atomic-free bucket fill using precomputed ranks ----
__global__ void build_ui_kernel(const int* __restrict__ rows, const int* __restrict__ cols,
                                const float* __restrict__ val,
                                const int* __restrict__ rankR, const int* __restrict__ rankC,
                                const int* __restrict__ ptr, int2* __restrict__ pk, int nnz) {
    int e = blockIdx.x * 256 + threadIdx.x;
    if (e >= nnz) return;
    int r = rows[e], c = cols[e];
    int vb = __float_as_int(val[e]);
    pk[ptr[B_UIR + r] + rankR[e]] = make_int2(c, vb);
    pk[ptr[B_UIC + c] + rankC[e]] = make_int2(r, vb);
}

__global__ void build1_kernel(const int* __restrict__ dest, const int* __restrict__ src,
                              const float* __restrict__ val, const int* __restrict__ rank,
                              const int* __restrict__ ptr_base, int2* __restrict__ pk, int nnz) {
    int e = blockIdx.x * 256 + threadIdx.x;
    if (e >= nnz) return;
    pk[ptr_base[dest[e]] + rank[e]] = make_int2(src[e], __float_as_int(val[e]));
}

// 4 edge-groups x float4 lanes; 8 edges in flight per wave.
// g = lane>>4 selects edge within the 8-pack, fl = lane&15 selects float4 of row.
__device__ __forceinline__ void acc_seg4(int b, int e, const int2* __restrict__ pk,
                                         const float4* __restrict__ src,
                                         int g, int fl, float4& acc) {
    for (int j = b; j < e; j += 8) {
        int j0 = j + g;
        int j1 = j + 4 + g;
        int i0 = (j0 < e) ? j0 : b;
        int i1 = (j1 < e) ? j1 : b;
        int2 q0 = pk[i0];
        int2 q1 = pk[i1];
        float v0 = (j0 < e) ? __int_as_float(q0.y) : 0.f;
        float v1 = (j1 < e) ? __int_as_float(q1.y) : 0.f;
        float4 x0 = src[q0.x * DV4 + fl];
        float4 x1 = src[q1.x * DV4 + fl];
        acc.x += v0 * x0.x; acc.y += v0 * x0.y; acc.z += v0 * x0.z; acc.w += v0 * x0.w;
        acc.x += v1 * x1.x; acc.y += v1 * x1.y; acc.z += v1 * x1.z; acc.w += v1 * x1.w;
    }
}

// One wave per output row (user rows then item rows).
__global__ void spmm_fused(const int* __restrict__ ptr, const int2* __restrict__ pk,
                           const float4* __restrict__ usrc, const float4* __restrict__ isrc,
                           float4* __restrict__ unext, float4* __restrict__ inext,
                           float4* __restrict__ outsum, float final_scale, int store_next) {
    int wave = (int)((blockIdx.x * 256 + threadIdx.x) >> 6);
    int lane = threadIdx.x & 63;
    if (wave >= NU + NI) return;
    int g = lane >> 4;
    int fl = lane & 15;

    const float4* srcA;
    const float4* srcB;
    int iA, iB;
    float4* dst;
    float4* op;
    if (wave < NU) {
        iA = B_UU + wave;                       // uu graph
        iB = B_UIR + wave;                      // ui by-row
        srcA = usrc; srcB = isrc;
        dst = unext + (size_t)wave * DV4;
        op  = outsum + (size_t)wave * DV4;
    } else {
        int r = wave - NU;
        iA = B_II + r;                          // ii graph
        iB = B_UIC + r;                         // ui by-col
        srcA = isrc; srcB = usrc;
        dst = inext + (size_t)r * DV4;
        op  = outsum + (size_t)(NU + r) * DV4;
    }

    float4 acc = make_float4(0.f, 0.f, 0.f, 0.f);
    acc_seg4(ptr[iA], ptr[iA + 1], pk, srcA, g, fl, acc);
    acc_seg4(ptr[iB], ptr[iB + 1], pk, srcB, g, fl, acc);

    // fold the 4 edge-groups (butterfly over lane bits 4,5)
    acc.x += __shfl_xor(acc.x, 16); acc.y += __shfl_xor(acc.y, 16);
    acc.z += __shfl_xor(acc.z, 16); acc.w += __shfl_xor(acc.w, 16);
    acc.x += __shfl_xor(acc.x, 32); acc.y += __shfl_xor(acc.y, 32);
    acc.z += __shfl_xor(acc.z, 32); acc.w += __shfl_xor(acc.w, 32);

    if (lane < 16) {
        float4 h;
        h.x = 0.5f * acc.x; h.y = 0.5f * acc.y; h.z = 0.5f * acc.z; h.w = 0.5f * acc.w;
        if (store_next) dst[fl] = h;
        float4 o = op[fl];
        o.x = (o.x + h.x) * final_scale;
        o.y = (o.y + h.y) * final_scale;
        o.z = (o.z + h.z) * final_scale;
        o.w = (o.w + h.w) * final_scale;
        op[fl] = o;
    }
}

extern "C" void kernel_launch(void* const* d_in, const int* in_sizes, int n_in,
                              void* d_out, int out_size, void* d_ws, size_t ws_size,
                              hipStream_t stream) {
    const float* ue      = (const float*)d_in[0];
    const float* ie      = (const float*)d_in[1];
    const float* uu_val  = (const float*)d_in[2];
    const float* ui_val  = (const float*)d_in[3];
    const float* ii_val  = (const float*)d_in[4];
    const int*   uu_rows = (const int*)d_in[5];
    const int*   uu_cols = (const int*)d_in[6];
    const int*   ui_rows = (const int*)d_in[7];
    const int*   ui_cols = (const int*)d_in[8];
    const int*   ii_rows = (const int*)d_in[9];
    const int*   ii_cols = (const int*)d_in[10];

    const int NNZ_UU = in_sizes[2];
    const int NNZ_UI = in_sizes[3];
    const int NNZ_II = in_sizes[4];
    const int NNZT   = 2 * NNZ_UI + NNZ_UU + NNZ_II;

    float* out = (float*)d_out;

    // ---- workspace layout ----
    float* wsf = (float*)d_ws;
    float* u_cur  = wsf;                        // NU*D
    float* i_cur  = u_cur + (size_t)NU * D;     // NI*D
    float* u_next = i_cur + (size_t)NI * D;     // NU*D
    float* i_next = u_next + (size_t)NU * D;    // NI*D
    int2*  pk     = (int2*)(i_next + (size_t)NI * D);   // NNZT int2
    int*   ptr    = (int*)(pk + NNZT);          // NTOT+1
    int*   cnt    = ptr + (NTOT + 1);           // NTOT
    int*   bsum   = cnt + NTOT;                 // NB
    int*   bscan  = bsum + NB;                  // NB
    // rank arrays alias u_next (only live between hist and build; u_next written later)
    int* rankR  = (int*)u_next;                 // NNZ_UI
    int* rankC  = rankR + NNZ_UI;               // NNZ_UI
    int* rankUU = rankC + NNZ_UI;               // NNZ_UU
    int* rankII = rankUU + NNZ_UU;              // NNZ_II

    hipMemsetAsync(cnt, 0, sizeof(int) * (size_t)NTOT, stream);

    init_kernel<<<(NT4 + 255) / 256, 256, 0, stream>>>(
        (const float4*)ue, (const float4*)ie, (float4*)out,
        (float4*)u_cur, (float4*)i_cur);

    // histograms (+ intra-bucket ranks)
    hist_ui_kernel<<<(NNZ_UI + 255) / 256, 256, 0, stream>>>(
        ui_rows, ui_cols, cnt, rankR, rankC, NNZ_UI);
    hist1_kernel<<<(NNZ_UU + 255) / 256, 256, 0, stream>>>(
        uu_rows, cnt + B_UU, rankUU, NNZ_UU);
    hist1_kernel<<<(NNZ_II + 255) / 256, 256, 0, stream>>>(
        ii_rows, cnt + B_II, rankII, NNZ_II);

    // hierarchical exclusive scan of all 4 count blocks at once
    scan_reduce<<<NB, 256, 0, stream>>>(cnt, bsum);
    scan_top<<<1, 512, 0, stream>>>(bsum, bscan, ptr);
    scan_write<<<NB, 256, 0, stream>>>(cnt, bscan, ptr);

    // atomic-free packed-edge fill
    build_ui_kernel<<<(NNZ_UI + 255) / 256, 256, 0, stream>>>(
        ui_rows, ui_cols, ui_val, rankR, rankC, ptr, pk, NNZ_UI);
    build1_kernel<<<(NNZ_UU + 255) / 256, 256, 0, stream>>>(
        uu_rows, uu_cols, uu_val, rankUU, ptr + B_UU, pk, NNZ_UU);
    build1_kernel<<<(NNZ_II + 255) / 256, 256, 0, stream>>>(
        ii_rows, ii_cols, ii_val, rankII, ptr + B_II, pk, NNZ_II);

    // ---- layer 1: cur -> next, out += h ----
    int blocks = ((NU + NI) * 64 + 255) / 256;
    spmm_fused<<<blocks, 256, 0, stream>>>(
        ptr, pk, (const float4*)u_cur, (const float4*)i_cur,
        (float4*)u_next, (float4*)i_next, (float4*)out, 1.0f, 1);

    // ---- layer 2: next -> (discard), out = (out + h)/3 ----
    spmm_fused<<<blocks, 256, 0, stream>>>(
        ptr, pk, (const float4*)u_next, (const float4*)i_next,
        (float4*)u_cur, (float4*)i_cur, (float4*)out, 1.0f / 3.0f, 0);
}

// Round 5
// 802.059 us; speedup vs baseline: 13.6236x; 1.2429x over previous
//
#include <hip/hip_runtime.h>

typedef _Float16 half8_t __attribute__((ext_vector_type(8)));
typedef _Float16 half4_t __attribute__((ext_vector_type(4)));

#define NU 100000
#define NI 50000
#define NR (NU + NI)                  // 150000 unified rows (users then items)
#define D 64
#define NTOT (2 * NR)                 // cnt layout: [uiR: NU | uiC: NI | uu: NU | ii: NI]
                                      // => for row w: segB bucket = w (ui), segA bucket = NR + w (uu/ii)
#define NB ((NTOT + 1023) / 1024)     // 293 scan blocks
#define NT4 (NR * 16)                 // float4 count of the full fp32 table

// out = concat(ue, ie) in fp32; curh = same data as fp16
__global__ void init_kernel(const float4* __restrict__ ue, const float4* __restrict__ ie,
                            float4* __restrict__ out, half4_t* __restrict__ curh) {
    int idx = blockIdx.x * 256 + threadIdx.x;
    if (idx >= NT4) return;
    float4 v = (idx < NU * 16) ? ue[idx] : ie[idx - NU * 16];
    out[idx] = v;
    half4_t h;
    h[0] = (_Float16)v.x; h[1] = (_Float16)v.y; h[2] = (_Float16)v.z; h[3] = (_Float16)v.w;
    curh[idx] = h;
}

// fused histogram over all 3 edge lists; rank = intra-bucket slot
__global__ void hist_all(const int* __restrict__ ui_r, const int* __restrict__ ui_c,
                         const int* __restrict__ uu_r, const int* __restrict__ ii_r,
                         int* __restrict__ cnt,
                         int* __restrict__ rankR, int* __restrict__ rankC,
                         int* __restrict__ rankUU, int* __restrict__ rankII,
                         int n_ui, int n_uu, int n_ii) {
    int t = blockIdx.x * 256 + threadIdx.x;
    if (t < n_ui) {
        rankR[t] = atomicAdd(&cnt[ui_r[t]], 1);
        rankC[t] = atomicAdd(&cnt[NU + ui_c[t]], 1);
    } else if (t < n_ui + n_uu) {
        int e = t - n_ui;
        rankUU[e] = atomicAdd(&cnt[NR + uu_r[e]], 1);
    } else if (t < n_ui + n_uu + n_ii) {
        int e = t - n_ui - n_uu;
        rankII[e] = atomicAdd(&cnt[NR + NU + ii_r[e]], 1);
    }
}

// ---- hierarchical exclusive scan over cnt[0..NTOT) ----
__global__ void scan_reduce(const int* __restrict__ cnt, int* __restrict__ bsum) {
    __shared__ int s[256];
    int tid = threadIdx.x;
    int base = blockIdx.x * 1024 + tid * 4;
    int sum = 0;
#pragma unroll
    for (int k = 0; k < 4; k++) {
        int i = base + k;
        if (i < NTOT) sum += cnt[i];
    }
    s[tid] = sum;
    __syncthreads();
    for (int off = 128; off > 0; off >>= 1) {
        if (tid < off) s[tid] += s[tid + off];
        __syncthreads();
    }
    if (tid == 0) bsum[blockIdx.x] = s[0];
}

__global__ void scan_top(const int* __restrict__ bsum, int* __restrict__ bscan,
                         int* __restrict__ ptr) {
    __shared__ int s[512];
    int tid = threadIdx.x;
    int x = (tid < NB) ? bsum[tid] : 0;
    s[tid] = x;
    __syncthreads();
    for (int off = 1; off < 512; off <<= 1) {
        int t = (tid >= off) ? s[tid - off] : 0;
        __syncthreads();
        s[tid] += t;
        __syncthreads();
    }
    if (tid < NB) bscan[tid] = s[tid] - x;   // exclusive
    if (tid == 511) ptr[NTOT] = s[511];      // total nnz
}

__global__ void scan_write(const int* __restrict__ cnt, const int* __restrict__ bscan,
                           int* __restrict__ ptr) {
    __shared__ int s[256];
    int tid = threadIdx.x;
    int base = blockIdx.x * 1024 + tid * 4;
    int c[4];
    int sum = 0;
#pragma unroll
    for (int k = 0; k < 4; k++) {
        int i = base + k;
        c[k] = (i < NTOT) ? cnt[i] : 0;
        sum += c[k];
    }
    s[tid] = sum;
    __syncthreads();
    for (int off = 1; off < 256; off <<= 1) {
        int t = (tid >= off) ? s[tid - off] : 0;
        __syncthreads();
        s[tid] += t;
        __syncthreads();
    }
    int run = s[tid] - sum + bscan[blockIdx.x];
#pragma unroll
    for (int k = 0; k < 4; k++) {
        int i = base + k;
        if (i < NTOT) ptr[i] = run;
        run += c[k];
    }
}

// fused atomic-free bucket fill; sources stored in the UNIFIED row space (items offset by NU)
__global__ void build_all(const int* __restrict__ ui_r, const int* __restrict__ ui_c,
                          const float* __restrict__ ui_v,
                          const int* __restrict__ uu_r, const int* __restrict__ uu_c,
                          const float* __restrict__ uu_v,
                          const int* __restrict__ ii_r, const int* __restrict__ ii_c,
                          const float* __restrict__ ii_v,
                          const int* __restrict__ rankR, const int* __restrict__ rankC,
                          const int* __restrict__ rankUU, const int* __restrict__ rankII,
                          const int* __restrict__ ptr, int2* __restrict__ pk,
                          int n_ui, int n_uu, int n_ii) {
    int t = blockIdx.x * 256 + threadIdx.x;
    if (t < n_ui) {
        int r = ui_r[t], c = ui_c[t];
        int vb = __float_as_int(ui_v[t]);
        pk[ptr[r] + rankR[t]]      = make_int2(NU + c, vb);  // user row gathers item
        pk[ptr[NU + c] + rankC[t]] = make_int2(r, vb);       // item row gathers user
    } else if (t < n_ui + n_uu) {
        int e = t - n_ui;
        int r = uu_r[e];
        pk[ptr[NR + r] + rankUU[e]] = make_int2(uu_c[e], __float_as_int(uu_v[e]));
    } else if (t < n_ui + n_uu + n_ii) {
        int e = t - n_ui - n_uu;
        int r = ii_r[e];
        pk[ptr[NR + NU + r] + rankII[e]] = make_int2(NU + ii_c[e], __float_as_int(ii_v[e]));
    }
}

// 8 edge-groups x 8 feature-lanes; 16 edges in flight per wave (2-deep unroll).
__device__ __forceinline__ void acc_seg(int b, int e, const int2* __restrict__ pk,
                                        const half8_t* __restrict__ src,
                                        int g, int fl, float* acc) {
    for (int j = b; j < e; j += 16) {
        int j0 = j + g;
        int j1 = j + 8 + g;
        int i0 = (j0 < e) ? j0 : b;
        int i1 = (j1 < e) ? j1 : b;
        int2 q0 = pk[i0];
        int2 q1 = pk[i1];
        float v0 = (j0 < e) ? __int_as_float(q0.y) : 0.f;
        float v1 = (j1 < e) ? __int_as_float(q1.y) : 0.f;
        half8_t x0 = src[q0.x * 8 + fl];
        half8_t x1 = src[q1.x * 8 + fl];
#pragma unroll
        for (int k = 0; k < 8; k++) acc[k] += v0 * (float)x0[k];
#pragma unroll
        for (int k = 0; k < 8; k++) acc[k] += v1 * (float)x1[k];
    }
}

// One wave per unified row w: segB = ui bucket (w), segA = uu/ii bucket (NR+w). Branchless.
__global__ void spmm_fused(const int* __restrict__ ptr, const int2* __restrict__ pk,
                           const half8_t* __restrict__ src,
                           half8_t* __restrict__ nexth, float4* __restrict__ out,
                           float final_scale, int store_next) {
    int w = (int)((blockIdx.x * 256 + threadIdx.x) >> 6);
    int lane = threadIdx.x & 63;
    if (w >= NR) return;
    int g = lane >> 3;
    int fl = lane & 7;

    float acc[8];
#pragma unroll
    for (int k = 0; k < 8; k++) acc[k] = 0.f;

    int sA = NR + w;
    acc_seg(ptr[sA], ptr[sA + 1], pk, src, g, fl, acc);
    acc_seg(ptr[w],  ptr[w + 1],  pk, src, g, fl, acc);

    // fold the 8 edge-groups (butterfly over lane bits 3,4,5)
#pragma unroll
    for (int k = 0; k < 8; k++) {
        acc[k] += __shfl_xor(acc[k], 8);
        acc[k] += __shfl_xor(acc[k], 16);
        acc[k] += __shfl_xor(acc[k], 32);
    }

    if (lane < 8) {
        float h[8];
#pragma unroll
        for (int k = 0; k < 8; k++) h[k] = 0.5f * acc[k];
        if (store_next) {
            half8_t hh;
#pragma unroll
            for (int k = 0; k < 8; k++) hh[k] = (_Float16)h[k];
            nexth[w * 8 + lane] = hh;
        }
        float4* op = out + (size_t)w * 16 + lane * 2;
        float4 o0 = op[0];
        float4 o1 = op[1];
        o0.x = (o0.x + h[0]) * final_scale;
        o0.y = (o0.y + h[1]) * final_scale;
        o0.z = (o0.z + h[2]) * final_scale;
        o0.w = (o0.w + h[3]) * final_scale;
        o1.x = (o1.x + h[4]) * final_scale;
        o1.y = (o1.y + h[5]) * final_scale;
        o1.z = (o1.z + h[6]) * final_scale;
        o1.w = (o1.w + h[7]) * final_scale;
        op[0] = o0;
        op[1] = o1;
    }
}

extern "C" void kernel_launch(void* const* d_in, const int* in_sizes, int n_in,
                              void* d_out, int out_size, void* d_ws, size_t ws_size,
                              hipStream_t stream) {
    const float* ue      = (const float*)d_in[0];
    const float* ie      = (const float*)d_in[1];
    const float* uu_val  = (const float*)d_in[2];
    const float* ui_val  = (const float*)d_in[3];
    const float* ii_val  = (const float*)d_in[4];
    const int*   uu_rows = (const int*)d_in[5];
    const int*   uu_cols = (const int*)d_in[6];
    const int*   ui_rows = (const int*)d_in[7];
    const int*   ui_cols = (const int*)d_in[8];
    const int*   ii_rows = (const int*)d_in[9];
    const int*   ii_cols = (const int*)d_in[10];

    const int NNZ_UU = in_sizes[2];
    const int NNZ_UI = in_sizes[3];
    const int NNZ_II = in_sizes[4];
    const int NNZT   = 2 * NNZ_UI + NNZ_UU + NNZ_II;
    const int NE     = NNZ_UI + NNZ_UU + NNZ_II;

    float* out = (float*)d_out;

    // ---- workspace layout (16B-aligned blocks first) ----
    char* wsb = (char*)d_ws;
    half8_t* curh  = (half8_t*)wsb;                               // NR*8 half8 = 19.2 MB
    half8_t* nexth = curh + (size_t)NR * 8;                       // 19.2 MB
    int2*    pk    = (int2*)(nexth + (size_t)NR * 8);             // NNZT * 8B = 51.2 MB
    int*     rankR = (int*)(pk + NNZT);                           // NNZ_UI
    int*     rankC = rankR + NNZ_UI;                              // NNZ_UI
    int*     rankUU = rankC + NNZ_UI;                             // NNZ_UU
    int*     rankII = rankUU + NNZ_UU;                            // NNZ_II
    int*     ptr   = rankII + NNZ_II;                             // NTOT+1
    int*     cnt   = ptr + (NTOT + 1);                            // NTOT
    int*     bsum  = cnt + NTOT;                                  // NB
    int*     bscan = bsum + NB;                                   // NB

    hipMemsetAsync(cnt, 0, sizeof(int) * (size_t)NTOT, stream);

    init_kernel<<<(NT4 + 255) / 256, 256, 0, stream>>>(
        (const float4*)ue, (const float4*)ie, (float4*)out, (half4_t*)curh);

    hist_all<<<(NE + 255) / 256, 256, 0, stream>>>(
        ui_rows, ui_cols, uu_rows, ii_rows, cnt,
        rankR, rankC, rankUU, rankII, NNZ_UI, NNZ_UU, NNZ_II);

    scan_reduce<<<NB, 256, 0, stream>>>(cnt, bsum);
    scan_top<<<1, 512, 0, stream>>>(bsum, bscan, ptr);
    scan_write<<<NB, 256, 0, stream>>>(cnt, bscan, ptr);

    build_all<<<(NE + 255) / 256, 256, 0, stream>>>(
        ui_rows, ui_cols, ui_val, uu_rows, uu_cols, uu_val,
        ii_rows, ii_cols, ii_val,
        rankR, rankC, rankUU, rankII, ptr, pk, NNZ_UI, NNZ_UU, NNZ_II);

    int blocks = (NR * 64 + 255) / 256;   // 4 waves (rows) per block

    // layer 1: gather curh -> nexth (fp16), out += h
    spmm_fused<<<blocks, 256, 0, stream>>>(
        ptr, pk, curh, nexth, (float4*)out, 1.0f, 1);

    // layer 2: gather nexth, out = (out + h) / 3
    spmm_fused<<<blocks, 256, 0, stream>>>(
        ptr, pk, nexth, curh, (float4*)out, 1.0f / 3.0f, 0);
}

// Round 6
// 691.473 us; speedup vs baseline: 15.8024x; 1.1599x over previous
//
#include <hip/hip_runtime.h>

typedef _Float16 half8_t __attribute__((ext_vector_type(8)));
typedef _Float16 half4_t __attribute__((ext_vector_type(4)));

#define NU 100000
#define NI 50000
#define NR (NU + NI)          // unified rows: users then items
#define D 64
#define COARSE 256
#define RPB 586               // rows per coarse bucket (586*256 = 150016 >= NR)
#define CHUNK 16384           // placements per block in count/place
#define NT4 (NR * 16)         // float4 count of full table

// out = concat(ue, ie) fp32; curh = same data fp16
__global__ void init_kernel(const float4* __restrict__ ue, const float4* __restrict__ ie,
                            float4* __restrict__ out, half4_t* __restrict__ curh) {
    int idx = blockIdx.x * 256 + threadIdx.x;
    if (idx >= NT4) return;
    float4 v = (idx < NU * 16) ? ue[idx] : ie[idx - NU * 16];
    out[idx] = v;
    half4_t h;
    h[0] = (_Float16)v.x; h[1] = (_Float16)v.y; h[2] = (_Float16)v.z; h[3] = (_Float16)v.w;
    curh[idx] = h;
}

// placement p -> dest row (merged bucket space, items offset by NU)
__device__ __forceinline__ int place_dest(int p, const int* ui_r, const int* ui_c,
                                          const int* uu_r, const int* ii_r,
                                          int n_ui, int n_uu) {
    if (p < 2 * n_ui) {
        int e = p >> 1;
        return (p & 1) ? NU + ui_c[e] : ui_r[e];
    } else if (p < 2 * n_ui + n_uu) {
        return uu_r[p - 2 * n_ui];
    } else {
        return NU + ii_r[p - 2 * n_ui - n_uu];
    }
}

// per-block coarse histogram -> m[block][256]
__global__ void count_kernel(const int* __restrict__ ui_r, const int* __restrict__ ui_c,
                             const int* __restrict__ uu_r, const int* __restrict__ ii_r,
                             int* __restrict__ m, int n_ui, int n_uu, int nnzt) {
    __shared__ int cnt[COARSE];
    int tid = threadIdx.x;
    if (tid < COARSE) cnt[tid] = 0;
    __syncthreads();
    int blk0 = blockIdx.x * CHUNK;
#pragma unroll
    for (int k = 0; k < 16; k++) {
        int p = blk0 + k * 1024 + tid;
        if (p < nnzt) {
            int dest = place_dest(p, ui_r, ui_c, uu_r, ii_r, n_ui, n_uu);
            atomicAdd(&cnt[dest / RPB], 1);
        }
    }
    __syncthreads();
    if (tid < COARSE) m[blockIdx.x * COARSE + tid] = cnt[tid];
}

// single block: column totals -> coarse_base (exclusive over buckets);
// rewrite m in place as per-block absolute base offsets; set ptr[NR].
__global__ void mid_kernel(int* __restrict__ m, int nblk,
                           int* __restrict__ coarse_base, int* __restrict__ ptr_nr) {
    __shared__ int s[COARSE];
    int tid = threadIdx.x;   // 256
    int tot = 0;
    for (int b = 0; b < nblk; b++) tot += m[b * COARSE + tid];
    s[tid] = tot;
    __syncthreads();
    // inclusive scan over 256
    for (int off = 1; off < COARSE; off <<= 1) {
        int t = (tid >= off) ? s[tid - off] : 0;
        __syncthreads();
        s[tid] += t;
        __syncthreads();
    }
    int excl = s[tid] - tot;
    coarse_base[tid] = excl;
    if (tid == COARSE - 1) {
        coarse_base[COARSE] = excl + tot;
        *ptr_nr = excl + tot;
    }
    int run = excl;
    for (int b = 0; b < nblk; b++) {
        int v = m[b * COARSE + tid];
        m[b * COARSE + tid] = run;
        run += v;
    }
}

// scatter packed records into coarse-partitioned scratch; NO global atomics
__global__ void place_kernel(const int* __restrict__ ui_r, const int* __restrict__ ui_c,
                             const float* __restrict__ ui_v,
                             const int* __restrict__ uu_r, const int* __restrict__ uu_c,
                             const float* __restrict__ uu_v,
                             const int* __restrict__ ii_r, const int* __restrict__ ii_c,
                             const float* __restrict__ ii_v,
                             const int* __restrict__ m, uint2* __restrict__ scratch,
                             int n_ui, int n_uu, int nnzt) {
    __shared__ int cnt[COARSE];
    __shared__ int base_s[COARSE];
    int tid = threadIdx.x;
    if (tid < COARSE) cnt[tid] = 0;
    __syncthreads();
    int blk0 = blockIdx.x * CHUNK;
    int rk[16];
#pragma unroll
    for (int k = 0; k < 16; k++) {
        int p = blk0 + k * 1024 + tid;
        rk[k] = -1;
        if (p < nnzt) {
            int dest = place_dest(p, ui_r, ui_c, uu_r, ii_r, n_ui, n_uu);
            int c = dest / RPB;
            int lr = atomicAdd(&cnt[c], 1);
            rk[k] = (c << 24) | lr;   // lr < 16384 fits
        }
    }
    __syncthreads();
    if (tid < COARSE) base_s[tid] = m[blockIdx.x * COARSE + tid];
    __syncthreads();
#pragma unroll
    for (int k = 0; k < 16; k++) {
        int p = blk0 + k * 1024 + tid;
        if (p >= nnzt) continue;
        int dest, src;
        float v;
        if (p < 2 * n_ui) {
            int e = p >> 1;
            int r = ui_r[e], cc = ui_c[e];
            v = ui_v[e];
            if (p & 1) { dest = NU + cc; src = r; }
            else       { dest = r; src = NU + cc; }
        } else if (p < 2 * n_ui + n_uu) {
            int e = p - 2 * n_ui;
            dest = uu_r[e]; src = uu_c[e]; v = uu_v[e];
        } else {
            int e = p - 2 * n_ui - n_uu;
            dest = NU + ii_r[e]; src = NU + ii_c[e]; v = ii_v[e];
        }
        int c  = ((unsigned)rk[k]) >> 24;
        int lr = rk[k] & 0xFFFFFF;
        int dl = dest - c * RPB;                  // < 586, 10 bits
        _Float16 hv = (_Float16)v;
        unsigned short us;
        __builtin_memcpy(&us, &hv, 2);
        scratch[base_s[c] + lr] = make_uint2(((unsigned)dl << 18) | (unsigned)src, (unsigned)us);
    }
}

// one block per coarse bucket: fine per-row histogram + scan in LDS -> ptr, pk arrays
__global__ void csr_kernel(const uint2* __restrict__ scratch, const int* __restrict__ coarse_base,
                           int* __restrict__ ptr, int* __restrict__ pk_src,
                           unsigned short* __restrict__ pk_val) {
    __shared__ int s[1024];
    __shared__ int fine[RPB];
    __shared__ int fill[RPB];
    int c = blockIdx.x, tid = threadIdx.x;
    int rbeg = c * RPB;
    int rcnt = NR - rbeg;
    if (rcnt > RPB) rcnt = RPB;
    int base = coarse_base[c], end = coarse_base[c + 1];
    for (int i = tid; i < RPB; i += 1024) fine[i] = 0;
    __syncthreads();
    for (int i = base + tid; i < end; i += 1024)
        atomicAdd(&fine[scratch[i].x >> 18], 1);
    __syncthreads();
    int own = (tid < rcnt) ? fine[tid] : 0;
    s[tid] = own;
    __syncthreads();
    for (int off = 1; off < 1024; off <<= 1) {
        int t = (tid >= off) ? s[tid - off] : 0;
        __syncthreads();
        s[tid] += t;
        __syncthreads();
    }
    int excl = s[tid] - own;
    if (tid < rcnt) {
        ptr[rbeg + tid] = base + excl;
        fill[tid] = excl;
    }
    __syncthreads();
    for (int i = base + tid; i < end; i += 1024) {
        uint2 rec = scratch[i];
        int dl = rec.x >> 18;
        int src = rec.x & 0x3FFFF;
        int slot = atomicAdd(&fill[dl], 1);
        pk_src[base + slot] = src;
        pk_val[base + slot] = (unsigned short)rec.y;
    }
}

// one wave per row; 8 edge-groups x 8 feature-lanes; 16 edges in flight
__global__ void spmm_fused(const int* __restrict__ ptr, const int* __restrict__ pk_src,
                           const _Float16* __restrict__ pk_val,
                           const half8_t* __restrict__ src,
                           half8_t* __restrict__ nexth, float4* __restrict__ out,
                           float final_scale, int store_next) {
    int w = (int)((blockIdx.x * 256 + threadIdx.x) >> 6);
    int lane = threadIdx.x & 63;
    if (w >= NR) return;
    int g = lane >> 3;
    int fl = lane & 7;

    int b = ptr[w], e = ptr[w + 1];
    float acc[8];
#pragma unroll
    for (int k = 0; k < 8; k++) acc[k] = 0.f;

    for (int j = b; j < e; j += 16) {
        int j0 = j + g;
        int j1 = j + 8 + g;
        int i0 = (j0 < e) ? j0 : b;
        int i1 = (j1 < e) ? j1 : b;
        int s0 = pk_src[i0];
        int s1 = pk_src[i1];
        float v0 = (j0 < e) ? (float)pk_val[i0] : 0.f;
        float v1 = (j1 < e) ? (float)pk_val[i1] : 0.f;
        half8_t x0 = src[s0 * 8 + fl];
        half8_t x1 = src[s1 * 8 + fl];
#pragma unroll
        for (int k = 0; k < 8; k++) acc[k] += v0 * (float)x0[k];
#pragma unroll
        for (int k = 0; k < 8; k++) acc[k] += v1 * (float)x1[k];
    }

#pragma unroll
    for (int k = 0; k < 8; k++) {
        acc[k] += __shfl_xor(acc[k], 8);
        acc[k] += __shfl_xor(acc[k], 16);
        acc[k] += __shfl_xor(acc[k], 32);
    }

    if (lane < 8) {
        float h[8];
#pragma unroll
        for (int k = 0; k < 8; k++) h[k] = 0.5f * acc[k];
        if (store_next) {
            half8_t hh;
#pragma unroll
            for (int k = 0; k < 8; k++) hh[k] = (_Float16)h[k];
            nexth[w * 8 + lane] = hh;
        }
        float4* op = out + (size_t)w * 16 + lane * 2;
        float4 o0 = op[0];
        float4 o1 = op[1];
        o0.x = (o0.x + h[0]) * final_scale;
        o0.y = (o0.y + h[1]) * final_scale;
        o0.z = (o0.z + h[2]) * final_scale;
        o0.w = (o0.w + h[3]) * final_scale;
        o1.x = (o1.x + h[4]) * final_scale;
        o1.y = (o1.y + h[5]) * final_scale;
        o1.z = (o1.z + h[6]) * final_scale;
        o1.w = (o1.w + h[7]) * final_scale;
        op[0] = o0;
        op[1] = o1;
    }
}

extern "C" void kernel_launch(void* const* d_in, const int* in_sizes, int n_in,
                              void* d_out, int out_size, void* d_ws, size_t ws_size,
                              hipStream_t stream) {
    const float* ue      = (const float*)d_in[0];
    const float* ie      = (const float*)d_in[1];
    const float* uu_val  = (const float*)d_in[2];
    const float* ui_val  = (const float*)d_in[3];
    const float* ii_val  = (const float*)d_in[4];
    const int*   uu_rows = (const int*)d_in[5];
    const int*   uu_cols = (const int*)d_in[6];
    const int*   ui_rows = (const int*)d_in[7];
    const int*   ui_cols = (const int*)d_in[8];
    const int*   ii_rows = (const int*)d_in[9];
    const int*   ii_cols = (const int*)d_in[10];

    const int NNZ_UU = in_sizes[2];
    const int NNZ_UI = in_sizes[3];
    const int NNZ_II = in_sizes[4];
    const int NNZT   = 2 * NNZ_UI + NNZ_UU + NNZ_II;
    const int NBLK   = (NNZT + CHUNK - 1) / CHUNK;

    float* out = (float*)d_out;

    // ---- workspace layout (16B-aligned blocks first), ~110 MB total ----
    char* wsb = (char*)d_ws;
    half8_t* curh   = (half8_t*)wsb;                         // NR*128 B = 19.2 MB
    uint2*   scratch = (uint2*)(wsb + (size_t)NR * 128);     // NNZT*8 = 51.2 MB
    half8_t* nexth  = (half8_t*)scratch;                     // aliases scratch (dead after csr)
    int*     pk_src = (int*)(scratch + NNZT);                // NNZT*4
    unsigned short* pk_val = (unsigned short*)(pk_src + NNZT); // NNZT*2 (even count -> 4B align after)
    int*     ptr    = (int*)(pk_val + NNZT);                 // NR+1
    int*     coarse_base = ptr + (NR + 1);                   // COARSE+1
    int*     m      = coarse_base + (COARSE + 1);            // NBLK*COARSE

    init_kernel<<<(NT4 + 255) / 256, 256, 0, stream>>>(
        (const float4*)ue, (const float4*)ie, (float4*)out, (half4_t*)curh);

    count_kernel<<<NBLK, 1024, 0, stream>>>(
        ui_rows, ui_cols, uu_rows, ii_rows, m, NNZ_UI, NNZ_UU, NNZT);

    mid_kernel<<<1, 256, 0, stream>>>(m, NBLK, coarse_base, ptr + NR);

    place_kernel<<<NBLK, 1024, 0, stream>>>(
        ui_rows, ui_cols, ui_val, uu_rows, uu_cols, uu_val,
        ii_rows, ii_cols, ii_val, m, scratch, NNZ_UI, NNZ_UU, NNZT);

    csr_kernel<<<COARSE, 1024, 0, stream>>>(scratch, coarse_base, ptr, pk_src, pk_val);

    int blocks = (NR * 64 + 255) / 256;   // 4 rows per block

    // layer 1: gather curh -> nexth, out += h
    spmm_fused<<<blocks, 256, 0, stream>>>(
        ptr, pk_src, (const _Float16*)pk_val, curh, nexth, (float4*)out, 1.0f, 1);

    // layer 2: gather nexth, out = (out + h) / 3
    spmm_fused<<<blocks, 256, 0, stream>>>(
        ptr, pk_src, (const _Float16*)pk_val, nexth, curh, (float4*)out, 1.0f / 3.0f, 0);
}

// Round 7
// 647.545 us; speedup vs baseline: 16.8744x; 1.0678x over previous
//
#include <hip/hip_runtime.h>

typedef _Float16 half8_t __attribute__((ext_vector_type(8)));
typedef _Float16 half4_t __attribute__((ext_vector_type(4)));

#define NU 100000
#define NI 50000
#define NR (NU + NI)          // unified rows: users then items
#define D 64
#define COARSE 1024
#define RPB 147               // rows per coarse bucket (147*1024 = 150528 >= NR)
#define CAP 8800              // LDS staging capacity per bucket (mean 6250, sigma ~79)
#define CHUNK 16384           // placements per block in count/place
#define NT4 (NR * 16)         // float4 count of full table

// out = concat(ue, ie) fp32; curh = same data fp16
__global__ void init_kernel(const float4* __restrict__ ue, const float4* __restrict__ ie,
                            float4* __restrict__ out, half4_t* __restrict__ curh) {
    int idx = blockIdx.x * 256 + threadIdx.x;
    if (idx >= NT4) return;
    float4 v = (idx < NU * 16) ? ue[idx] : ie[idx - NU * 16];
    out[idx] = v;
    half4_t h;
    h[0] = (_Float16)v.x; h[1] = (_Float16)v.y; h[2] = (_Float16)v.z; h[3] = (_Float16)v.w;
    curh[idx] = h;
}

// placement p -> dest row (unified row space, items offset by NU)
__device__ __forceinline__ int place_dest(int p, const int* ui_r, const int* ui_c,
                                          const int* uu_r, const int* ii_r,
                                          int n_ui, int n_uu) {
    if (p < 2 * n_ui) {
        int e = p >> 1;
        return (p & 1) ? NU + ui_c[e] : ui_r[e];
    } else if (p < 2 * n_ui + n_uu) {
        return uu_r[p - 2 * n_ui];
    } else {
        return NU + ii_r[p - 2 * n_ui - n_uu];
    }
}

// per-block coarse histogram -> m[block][COARSE]
__global__ void count_kernel(const int* __restrict__ ui_r, const int* __restrict__ ui_c,
                             const int* __restrict__ uu_r, const int* __restrict__ ii_r,
                             int* __restrict__ m, int n_ui, int n_uu, int nnzt) {
    __shared__ int cnt[COARSE];
    int tid = threadIdx.x;
    cnt[tid] = 0;
    __syncthreads();
    int blk0 = blockIdx.x * CHUNK;
#pragma unroll
    for (int k = 0; k < 16; k++) {
        int p = blk0 + k * 1024 + tid;
        if (p < nnzt) {
            int dest = place_dest(p, ui_r, ui_c, uu_r, ii_r, n_ui, n_uu);
            atomicAdd(&cnt[dest / RPB], 1);
        }
    }
    __syncthreads();
    m[blockIdx.x * COARSE + tid] = cnt[tid];
}

// single block, 1024 threads: column totals -> coarse_base (exclusive);
// rewrite m in place as per-block absolute base offsets; set ptr[NR].
__global__ void mid_kernel(int* __restrict__ m, int nblk,
                           int* __restrict__ coarse_base, int* __restrict__ ptr_nr) {
    __shared__ int s[COARSE];
    int tid = threadIdx.x;   // 1024
    int tot = 0;
    for (int b = 0; b < nblk; b++) tot += m[b * COARSE + tid];
    s[tid] = tot;
    __syncthreads();
    for (int off = 1; off < COARSE; off <<= 1) {
        int t = (tid >= off) ? s[tid - off] : 0;
        __syncthreads();
        s[tid] += t;
        __syncthreads();
    }
    int excl = s[tid] - tot;
    coarse_base[tid] = excl;
    if (tid == COARSE - 1) {
        coarse_base[COARSE] = excl + tot;
        *ptr_nr = excl + tot;
    }
    int run = excl;
    for (int b = 0; b < nblk; b++) {
        int v = m[b * COARSE + tid];
        m[b * COARSE + tid] = run;
        run += v;
    }
}

// scatter packed records into coarse-partitioned scratch; NO global atomics
__global__ void place_kernel(const int* __restrict__ ui_r, const int* __restrict__ ui_c,
                             const float* __restrict__ ui_v,
                             const int* __restrict__ uu_r, const int* __restrict__ uu_c,
                             const float* __restrict__ uu_v,
                             const int* __restrict__ ii_r, const int* __restrict__ ii_c,
                             const float* __restrict__ ii_v,
                             const int* __restrict__ m, uint2* __restrict__ scratch,
                             int n_ui, int n_uu, int nnzt) {
    __shared__ int cnt[COARSE];
    __shared__ int base_s[COARSE];
    int tid = threadIdx.x;
    cnt[tid] = 0;
    __syncthreads();
    int blk0 = blockIdx.x * CHUNK;
    int rk[16];
#pragma unroll
    for (int k = 0; k < 16; k++) {
        int p = blk0 + k * 1024 + tid;
        rk[k] = -1;
        if (p < nnzt) {
            int dest = place_dest(p, ui_r, ui_c, uu_r, ii_r, n_ui, n_uu);
            int c = dest / RPB;
            int lr = atomicAdd(&cnt[c], 1);   // lr < 16384 -> 14 bits
            rk[k] = (c << 14) | lr;
        }
    }
    __syncthreads();
    base_s[tid] = m[blockIdx.x * COARSE + tid];
    __syncthreads();
#pragma unroll
    for (int k = 0; k < 16; k++) {
        int p = blk0 + k * 1024 + tid;
        if (p >= nnzt) continue;
        int dest, src;
        float v;
        if (p < 2 * n_ui) {
            int e = p >> 1;
            int r = ui_r[e], cc = ui_c[e];
            v = ui_v[e];
            if (p & 1) { dest = NU + cc; src = r; }
            else       { dest = r; src = NU + cc; }
        } else if (p < 2 * n_ui + n_uu) {
            int e = p - 2 * n_ui;
            dest = uu_r[e]; src = uu_c[e]; v = uu_v[e];
        } else {
            int e = p - 2 * n_ui - n_uu;
            dest = NU + ii_r[e]; src = NU + ii_c[e]; v = ii_v[e];
        }
        int c  = rk[k] >> 14;
        int lr = rk[k] & 0x3FFF;
        int dl = dest - c * RPB;                  // < 147, 8 bits
        _Float16 hv = (_Float16)v;
        unsigned short us;
        __builtin_memcpy(&us, &hv, 2);
        scratch[base_s[c] + lr] = make_uint2(((unsigned)dl << 18) | (unsigned)src, (unsigned)us);
    }
}

// one block per coarse bucket: fine histogram + scan in LDS, scatter into LDS
// staging arrays, then fully-coalesced streamed writeout of pk_src / pk_val.
__global__ void csr_kernel(const uint2* __restrict__ scratch, const int* __restrict__ coarse_base,
                           int* __restrict__ ptr, int* __restrict__ pk_src,
                           unsigned short* __restrict__ pk_val) {
    __shared__ int s[1024];
    __shared__ int fine[256];            // RPB=147 padded
    __shared__ int fill[256];
    __shared__ int lsrc[CAP];            // 35.2 KB
    __shared__ unsigned short lval[CAP]; // 17.6 KB
    int c = blockIdx.x, tid = threadIdx.x;
    int rbeg = c * RPB;
    int rcnt = NR - rbeg;
    if (rcnt > RPB) rcnt = RPB;
    if (rcnt < 0) rcnt = 0;
    int base = coarse_base[c], end = coarse_base[c + 1];
    int n = end - base;
    if (tid < 256) { fine[tid] = 0; }
    __syncthreads();
    // pass 1: fine histogram
    for (int i = tid; i < n; i += 1024)
        atomicAdd(&fine[scratch[base + i].x >> 18], 1);
    __syncthreads();
    // exclusive scan (1024-wide Hillis-Steele over padded 256 counts)
    int own = (tid < 256) ? fine[tid] : 0;
    s[tid] = own;
    __syncthreads();
    for (int off = 1; off < 256; off <<= 1) {
        int t = (tid >= off) ? s[tid - off] : 0;
        __syncthreads();
        s[tid] += t;
        __syncthreads();
    }
    int excl = s[tid] - own;
    if (tid < rcnt) ptr[rbeg + tid] = base + excl;
    if (tid < 256) fill[tid] = excl;
    __syncthreads();
    if (n <= CAP) {
        // pass 2: scatter into LDS staging
        for (int i = tid; i < n; i += 1024) {
            uint2 rec = scratch[base + i];
            int dl = rec.x >> 18;
            int slot = atomicAdd(&fill[dl], 1);
            lsrc[slot] = rec.x & 0x3FFFF;
            lval[slot] = (unsigned short)rec.y;
        }
        __syncthreads();
        // pass 3: coalesced writeout
        for (int i = tid; i < n; i += 1024) {
            pk_src[base + i] = lsrc[i];
            pk_val[base + i] = lval[i];
        }
    } else {
        // overflow fallback: direct global scatter (block-uniform branch)
        for (int i = tid; i < n; i += 1024) {
            uint2 rec = scratch[base + i];
            int dl = rec.x >> 18;
            int slot = atomicAdd(&fill[dl], 1);
            pk_src[base + slot] = rec.x & 0x3FFFF;
            pk_val[base + slot] = (unsigned short)rec.y;
        }
    }
}

// one wave per row; 8 edge-groups x 8 feature-lanes; 32 edges in flight
__global__ void spmm_fused(const int* __restrict__ ptr, const int* __restrict__ pk_src,
                           const _Float16* __restrict__ pk_val,
                           const half8_t* __restrict__ src,
                           half8_t* __restrict__ nexth, float4* __restrict__ out,
                           float final_scale, int store_next) {
    int w = (int)((blockIdx.x * 256 + threadIdx.x) >> 6);
    int lane = threadIdx.x & 63;
    if (w >= NR) return;
    int g = lane >> 3;
    int fl = lane & 7;

    int b = ptr[w], e = ptr[w + 1];
    float acc[8];
#pragma unroll
    for (int k = 0; k < 8; k++) acc[k] = 0.f;

    for (int j = b; j < e; j += 32) {
#pragma unroll
        for (int t = 0; t < 4; t++) {
            int jt = j + 8 * t + g;
            int it = (jt < e) ? jt : b;
            int st = pk_src[it];
            float vt = (jt < e) ? (float)pk_val[it] : 0.f;
            half8_t xt = src[st * 8 + fl];
#pragma unroll
            for (int k = 0; k < 8; k++) acc[k] += vt * (float)xt[k];
        }
    }

#pragma unroll
    for (int k = 0; k < 8; k++) {
        acc[k] += __shfl_xor(acc[k], 8);
        acc[k] += __shfl_xor(acc[k], 16);
        acc[k] += __shfl_xor(acc[k], 32);
    }

    if (lane < 8) {
        float h[8];
#pragma unroll
        for (int k = 0; k < 8; k++) h[k] = 0.5f * acc[k];
        if (store_next) {
            half8_t hh;
#pragma unroll
            for (int k = 0; k < 8; k++) hh[k] = (_Float16)h[k];
            nexth[w * 8 + lane] = hh;
        }
        float4* op = out + (size_t)w * 16 + lane * 2;
        float4 o0 = op[0];
        float4 o1 = op[1];
        o0.x = (o0.x + h[0]) * final_scale;
        o0.y = (o0.y + h[1]) * final_scale;
        o0.z = (o0.z + h[2]) * final_scale;
        o0.w = (o0.w + h[3]) * final_scale;
        o1.x = (o1.x + h[4]) * final_scale;
        o1.y = (o1.y + h[5]) * final_scale;
        o1.z = (o1.z + h[6]) * final_scale;
        o1.w = (o1.w + h[7]) * final_scale;
        op[0] = o0;
        op[1] = o1;
    }
}

extern "C" void kernel_launch(void* const* d_in, const int* in_sizes, int n_in,
                              void* d_out, int out_size, void* d_ws, size_t ws_size,
                              hipStream_t stream) {
    const float* ue      = (const float*)d_in[0];
    const float* ie      = (const float*)d_in[1];
    const float* uu_val  = (const float*)d_in[2];
    const float* ui_val  = (const float*)d_in[3];
    const float* ii_val  = (const float*)d_in[4];
    const int*   uu_rows = (const int*)d_in[5];
    const int*   uu_cols = (const int*)d_in[6];
    const int*   ui_rows = (const int*)d_in[7];
    const int*   ui_cols = (const int*)d_in[8];
    const int*   ii_rows = (const int*)d_in[9];
    const int*   ii_cols = (const int*)d_in[10];

    const int NNZ_UU = in_sizes[2];
    const int NNZ_UI = in_sizes[3];
    const int NNZ_II = in_sizes[4];
    const int NNZT   = 2 * NNZ_UI + NNZ_UU + NNZ_II;
    const int NBLK   = (NNZT + CHUNK - 1) / CHUNK;

    float* out = (float*)d_out;

    // ---- workspace layout (16B-aligned blocks first), ~112 MB total ----
    char* wsb = (char*)d_ws;
    half8_t* curh   = (half8_t*)wsb;                         // NR*128 B = 19.2 MB
    uint2*   scratch = (uint2*)(wsb + (size_t)NR * 128);     // NNZT*8 = 51.2 MB
    half8_t* nexth  = (half8_t*)scratch;                     // aliases scratch (dead after csr)
    int*     pk_src = (int*)(scratch + NNZT);                // NNZT*4
    unsigned short* pk_val = (unsigned short*)(pk_src + NNZT); // NNZT*2
    int*     ptr    = (int*)(pk_val + NNZT);                 // NR+1
    int*     coarse_base = ptr + (NR + 1);                   // COARSE+1
    int*     m      = coarse_base + (COARSE + 1);            // NBLK*COARSE

    init_kernel<<<(NT4 + 255) / 256, 256, 0, stream>>>(
        (const float4*)ue, (const float4*)ie, (float4*)out, (half4_t*)curh);

    count_kernel<<<NBLK, 1024, 0, stream>>>(
        ui_rows, ui_cols, uu_rows, ii_rows, m, NNZ_UI, NNZ_UU, NNZT);

    mid_kernel<<<1, 1024, 0, stream>>>(m, NBLK, coarse_base, ptr + NR);

    place_kernel<<<NBLK, 1024, 0, stream>>>(
        ui_rows, ui_cols, ui_val, uu_rows, uu_cols, uu_val,
        ii_rows, ii_cols, ii_val, m, scratch, NNZ_UI, NNZ_UU, NNZT);

    csr_kernel<<<COARSE, 1024, 0, stream>>>(scratch, coarse_base, ptr, pk_src, pk_val);

    int blocks = (NR * 64 + 255) / 256;   // 4 rows per block

    // layer 1: gather curh -> nexth, out += h
    spmm_fused<<<blocks, 256, 0, stream>>>(
        ptr, pk_src, (const _Float16*)pk_val, curh, nexth, (float4*)out, 1.0f, 1);

    // layer 2: gather nexth, out = (out + h) / 3
    spmm_fused<<<blocks, 256, 0, stream>>>(
        ptr, pk_src, (const _Float16*)pk_val, nexth, curh, (float4*)out, 1.0f / 3.0f, 0);
}